// Round 13
// baseline (372.846 us; speedup 1.0000x reference)
//
#include <hip/hip_runtime.h>
#include <hip/hip_fp16.h>
#include <math.h>

// Problem constants (match reference)
#define NN     50000
#define EE     800000
#define ETOT   (EE + NN)      // edges + self loops = 850000
#define INDIM  128
#define HEADS  4
#define NG     128
#define NEGS   0.2f
#define BNEPS  1e-5f

typedef _Float16 half8 __attribute__((ext_vector_type(8)));
typedef _Float16 half4v __attribute__((ext_vector_type(4)));
typedef float floatx4 __attribute__((ext_vector_type(4)));

// R13: edge_aggr eighth-wave edge parallelism — 8 lanes per edge, each lane
// covers 8 channels via one fp16x8 (16B) gather; 8 lanes x 16B = full 128B
// row. Unroll 2 -> 16 edges/iter with HALF the gather instructions of R12's
// quarter-wave. Combine: shfl_xor(8)+(16)+(32) over z + acc[8].

// ---------------------------------------------------------------------------
// CSR build. R6: rank captured in degree_kernel (already pays the random
// atomic); scatter is atomic-free. R11: csr = src only (4B scatter payload).
__global__ void degree_kernel(const int* __restrict__ ei, int* __restrict__ deg,
                              int* __restrict__ rank) {
    int e = blockIdx.x * blockDim.x + threadIdx.x;
    if (e >= ETOT) return;
    int d = (e < EE) ? ei[EE + e] : (e - EE);
    rank[e] = atomicAdd(&deg[d], 1);
}

__global__ void scan_block_kernel(const int* __restrict__ deg, int* __restrict__ rowstart,
                                  int* __restrict__ bsums) {
    __shared__ int tmp[1024];
    int tid = threadIdx.x;
    int i = blockIdx.x * 1024 + tid;
    int v = (i < NN) ? deg[i] : 0;
    tmp[tid] = v;
    __syncthreads();
    for (int off = 1; off < 1024; off <<= 1) {
        int t = (tid >= off) ? tmp[tid - off] : 0;
        __syncthreads();
        tmp[tid] += t;
        __syncthreads();
    }
    if (i < NN) rowstart[i] = tmp[tid] - v;   // exclusive
    if (tid == 1023) bsums[blockIdx.x] = tmp[tid];
}

__global__ void scan_sums_kernel(int* __restrict__ bsums, int nb) {
    if (threadIdx.x == 0 && blockIdx.x == 0) {
        int acc = 0;
        for (int i = 0; i < nb; ++i) { int t = bsums[i]; bsums[i] = acc; acc += t; }
    }
}

__global__ void add_offsets_kernel(int* __restrict__ rowstart, const int* __restrict__ bsums) {
    int i = blockIdx.x * blockDim.x + threadIdx.x;
    if (i < NN) rowstart[i] += bsums[i >> 10];
}

// Atomic-free scatter, 4B payload (src only).
__global__ void scatter_kernel(const int* __restrict__ ei, const int* __restrict__ rowstart,
                               const int* __restrict__ rank, int* __restrict__ csr) {
    int e = blockIdx.x * blockDim.x + threadIdx.x;
    if (e >= ETOT) return;
    int s, d;
    if (e < EE) { s = ei[e]; d = ei[EE + e]; }
    else        { s = e - EE; d = e - EE; }
    int pos = rowstart[d] + rank[e];
    csr[pos] = s;
}

// ---------------------------------------------------------------------------
// Fused prep: fp32->fp16 converts (X, all W) + zero-init deg/psums/pcnt.
#define NX8 (NN * INDIM / 8)
#define PREP_TOT (NX8 + 2048 + NN + NG * 64 + NG)
__global__ __launch_bounds__(256) void prep_kernel(const float* __restrict__ x,
                                                   const float* __restrict__ W0,
                                                   const float* __restrict__ W1,
                                                   const float* __restrict__ W2,
                                                   _Float16* __restrict__ Xh,
                                                   _Float16* __restrict__ Wh,
                                                   int* __restrict__ deg,
                                                   float* __restrict__ psums,
                                                   int* __restrict__ pcnt) {
    int i = blockIdx.x * blockDim.x + threadIdx.x;     // x8 floats
    if (i < NX8) {
        float4 v0 = *(const float4*)(x + (size_t)i * 8);
        float4 v1 = *(const float4*)(x + (size_t)i * 8 + 4);
        half8 o;
        o[0] = (_Float16)v0.x; o[1] = (_Float16)v0.y;
        o[2] = (_Float16)v0.z; o[3] = (_Float16)v0.w;
        o[4] = (_Float16)v1.x; o[5] = (_Float16)v1.y;
        o[6] = (_Float16)v1.z; o[7] = (_Float16)v1.w;
        *(half8*)(Xh + (size_t)i * 8) = o;
    } else if (i < NX8 + 2048) {
        int wi = (i - NX8) * 8;            // 8-groups never straddle W arrays
#pragma unroll
        for (int j = 0; j < 8; ++j) {
            int idx = wi + j;
            float v = (idx < 8192) ? W0[idx]
                    : ((idx < 12288) ? W1[idx - 8192] : W2[idx - 12288]);
            Wh[idx] = (_Float16)v;
        }
    } else if (i < NX8 + 2048 + NN) {
        deg[i - NX8 - 2048] = 0;
    } else if (i < NX8 + 2048 + NN + NG * 64) {
        psums[i - NX8 - 2048 - NN] = 0.f;
    } else if (i < PREP_TOT) {
        pcnt[i - NX8 - 2048 - NN - NG * 64] = 0;
    }
}

// ---------------------------------------------------------------------------
// MFMA GEMM (h = x @ W^T) + attention dots. Block = 4 waves; each wave owns
// 16 nodes x 64 cols = 4 col-tiles of 16x16, K in 32-chunks.
// A frag: X[wbase + (lane&15)][kb*32 + quad*8 ..+8]; B frag same shape on W.
// C/D: node = wbase + quad*4 + reg, col = t*16 + (lane&15).
template <int DD>
__global__ __launch_bounds__(256) void gemm_att_kernel(
    const _Float16* __restrict__ X, const _Float16* __restrict__ Wh,
    const float* __restrict__ attS, const float* __restrict__ attD,
    _Float16* __restrict__ H, float* __restrict__ AS, float* __restrict__ AD) {
    constexpr int KB = DD / 32;
    int tid = threadIdx.x;
    int wv = tid >> 6;
    int lane = tid & 63;
    int quad = lane >> 4;
    int n = lane & 15;
    int wbase = blockIdx.x * 64 + wv * 16;

    int arow = wbase + n;
    if (arow >= NN) arow = NN - 1;          // clamp (stores are guarded)
    half8 a[KB];
#pragma unroll
    for (int kb = 0; kb < KB; ++kb)
        a[kb] = *(const half8*)(X + (size_t)arow * DD + kb * 32 + quad * 8);

    floatx4 c[4];
#pragma unroll
    for (int t = 0; t < 4; ++t) {
        floatx4 acc = {0.f, 0.f, 0.f, 0.f};
#pragma unroll
        for (int kb = 0; kb < KB; ++kb) {
            half8 b = *(const half8*)(Wh + (size_t)(t * 16 + n) * DD + kb * 32 + quad * 8);
            acc = __builtin_amdgcn_mfma_f32_16x16x32_f16(a[kb], b, acc, 0, 0, 0);
        }
        c[t] = acc;
    }

    float as_l[4], ad_l[4];
#pragma unroll
    for (int t = 0; t < 4; ++t) {
        as_l[t] = attS[t * 16 + n];
        ad_l[t] = attD[t * 16 + n];
    }
#pragma unroll
    for (int r = 0; r < 4; ++r) {
        int node = wbase + quad * 4 + r;
        bool ok = node < NN;
#pragma unroll
        for (int t = 0; t < 4; ++t) {
            float h = c[t][r];
            if (ok) H[(size_t)node * 64 + t * 16 + n] = (_Float16)h;
            float vs = h * as_l[t];
            float vd = h * ad_l[t];
#pragma unroll
            for (int off = 8; off; off >>= 1) {
                vs += __shfl_down(vs, off, 16);
                vd += __shfl_down(vd, off, 16);
            }
            if (ok && n == 0) {
                AS[node * 4 + t] = vs;
                AD[node * 4 + t] = vd;
            }
        }
    }
}

// ---------------------------------------------------------------------------
// Per-node aggregation, eighth-wave edge parallelism (R13).
// Group g = lane>>3 serves edges k+g*2, k+g*2+1 per 16-edge iteration; each
// lane covers 8 channels (ch8 = (lane&7)*8, head = (lane&7)>>1) via fp16x8
// (16B) gathers — 8 lanes x 16B = full 128B row per group. Cross-group
// combine: shfl_xor(8)+(16)+(32). Inline attention weights (R7); no
// max-subtraction (logits O(1), exp cannot overflow).
template <bool WRITE_Z>
__global__ __launch_bounds__(256) void edge_aggr_kernel(
    const _Float16* __restrict__ H, const float* __restrict__ AS,
    const float* __restrict__ AD,
    const int* __restrict__ rowstart, const int* __restrict__ deg,
    const int* __restrict__ csr,
    const float* __restrict__ bias, const float* __restrict__ gamma,
    const float* __restrict__ beta, const float* __restrict__ mean,
    const float* __restrict__ var, _Float16* __restrict__ Hout,
    float* __restrict__ Z) {
    int v = (blockIdx.x * blockDim.x + threadIdx.x) >> 6;
    if (v >= NN) return;
    int lane = threadIdx.x & 63;
    int g = lane >> 3;          // 0..7, edge group
    int l8 = lane & 7;
    int head = l8 >> 1;
    int ch8 = l8 * 8;
    float adv = AD[v * 4 + head];
    int start = rowstart[v];
    int cnt = deg[v];                    // >= 1 (self loop)
    const int* srow = csr + start;
    float z = 0.f;
    float acc[8] = {0.f, 0.f, 0.f, 0.f, 0.f, 0.f, 0.f, 0.f};
    int k = 0;
    for (; k + 16 <= cnt; k += 16) {
        int b = k + g * 2;
        int s0 = srow[b + 0];
        int s1 = srow[b + 1];
        float a0 = AS[(size_t)s0 * 4 + head];
        float a1 = AS[(size_t)s1 * 4 + head];
        half8 h0 = *(const half8*)(H + (size_t)s0 * 64 + ch8);
        half8 h1 = *(const half8*)(H + (size_t)s1 * 64 + ch8);
        float l0 = a0 + adv; l0 = l0 > 0.f ? l0 : NEGS * l0; float p0 = __expf(l0);
        float l1 = a1 + adv; l1 = l1 > 0.f ? l1 : NEGS * l1; float p1 = __expf(l1);
        z += p0 + p1;
#pragma unroll
        for (int j = 0; j < 8; ++j) {
            acc[j] = fmaf(p0, (float)h0[j], acc[j]);
            acc[j] = fmaf(p1, (float)h1[j], acc[j]);
        }
    }
    for (; k < cnt; k += 8) {
        int idx = k + g;
        if (idx < cnt) {
            int s = srow[idx];
            float a = AS[(size_t)s * 4 + head];
            half8 hv = *(const half8*)(H + (size_t)s * 64 + ch8);
            float l = a + adv; l = l > 0.f ? l : NEGS * l;
            float p = __expf(l);
            z += p;
#pragma unroll
            for (int j = 0; j < 8; ++j)
                acc[j] = fmaf(p, (float)hv[j], acc[j]);
        }
    }
    // combine the eight group partial sums
    z += __shfl_xor(z, 8); z += __shfl_xor(z, 16); z += __shfl_xor(z, 32);
#pragma unroll
    for (int j = 0; j < 8; ++j) {
        acc[j] += __shfl_xor(acc[j], 8);
        acc[j] += __shfl_xor(acc[j], 16);
        acc[j] += __shfl_xor(acc[j], 32);
    }
    if (g == 0) {
        if (WRITE_Z && (l8 & 1) == 0) Z[v * 4 + head] = z;
        float4 bi0 = *(const float4*)(bias + ch8);
        float4 bi1 = *(const float4*)(bias + ch8 + 4);
        float4 ga0 = *(const float4*)(gamma + ch8);
        float4 ga1 = *(const float4*)(gamma + ch8 + 4);
        float4 be0 = *(const float4*)(beta + ch8);
        float4 be1 = *(const float4*)(beta + ch8 + 4);
        float4 mu0 = *(const float4*)(mean + ch8);
        float4 mu1 = *(const float4*)(mean + ch8 + 4);
        float4 va0 = *(const float4*)(var + ch8);
        float4 va1 = *(const float4*)(var + ch8 + 4);
        float bi[8] = {bi0.x, bi0.y, bi0.z, bi0.w, bi1.x, bi1.y, bi1.z, bi1.w};
        float ga[8] = {ga0.x, ga0.y, ga0.z, ga0.w, ga1.x, ga1.y, ga1.z, ga1.w};
        float be[8] = {be0.x, be0.y, be0.z, be0.w, be1.x, be1.y, be1.z, be1.w};
        float mu[8] = {mu0.x, mu0.y, mu0.z, mu0.w, mu1.x, mu1.y, mu1.z, mu1.w};
        float va[8] = {va0.x, va0.y, va0.z, va0.w, va1.x, va1.y, va1.z, va1.w};
        half8 o;
#pragma unroll
        for (int j = 0; j < 8; ++j) {
            float r = fmaxf(acc[j] / z + bi[j], 0.f);
            r = ga[j] * (r - mu[j]) * rsqrtf(va[j] + BNEPS) + be[j];
            o[j] = (_Float16)r;
        }
        *(half8*)(Hout + (size_t)v * 64 + ch8) = o;
    }
}

// ---------------------------------------------------------------------------
// Layer-0 alpha, ORIGINAL edge order (R11): needs no csr; recomputes p from
// AS/AD (identical formula+inputs as aggr => identical values), divides by Z,
// writes coalesced float4 at alpha_out + e*4.
__global__ __launch_bounds__(256) void alpha_kernel(
    const int* __restrict__ ei,
    const float* __restrict__ AS, const float* __restrict__ AD,
    const float* __restrict__ Z, float* __restrict__ alpha_out) {
    int e = blockIdx.x * blockDim.x + threadIdx.x;
    if (e >= ETOT) return;
    int s, d;
    if (e < EE) { s = ei[e]; d = ei[EE + e]; }
    else        { s = e - EE; d = e - EE; }
    float4 as = *(const float4*)(AS + (size_t)s * 4);
    float4 ad = *(const float4*)(AD + (size_t)d * 4);
    float4 z4 = *(const float4*)(Z + (size_t)d * 4);
    float l;
    float4 a;
    l = as.x + ad.x; l = l > 0.f ? l : NEGS * l; a.x = __expf(l) / z4.x;
    l = as.y + ad.y; l = l > 0.f ? l : NEGS * l; a.y = __expf(l) / z4.y;
    l = as.z + ad.z; l = l > 0.f ? l : NEGS * l; a.z = __expf(l) / z4.z;
    l = as.w + ad.w; l = l > 0.f ? l : NEGS * l; a.w = __expf(l) / z4.w;
    *(float4*)(alpha_out + (size_t)e * 4) = a;
}

// ---------------------------------------------------------------------------
// Mean pool over sorted batch ids (fp16 input): one wave per 64-node chunk,
// local accumulation, atomic flush on graph-id change.
__global__ __launch_bounds__(256) void pool_kernel(const __half* __restrict__ H,
                                                   const int* __restrict__ batch,
                                                   float* __restrict__ sums,
                                                   int* __restrict__ cnt) {
    int wid = (blockIdx.x * blockDim.x + threadIdx.x) >> 6;
    int lane = threadIdx.x & 63;
    int base = wid * 64;
    if (base >= NN) return;
    int end = min(base + 64, NN);
    int cur = batch[base];
    float acc = 0.f;
    int c0 = 0;
    for (int i = base; i < end; ++i) {
        int g = batch[i];
        if (g != cur) {
            atomicAdd(&sums[cur * 64 + lane], acc);
            if (lane == 0) atomicAdd(&cnt[cur], c0);
            cur = g; acc = 0.f; c0 = 0;
        }
        acc += __half2float(H[(size_t)i * 64 + lane]);
        c0++;
    }
    atomicAdd(&sums[cur * 64 + lane], acc);
    if (lane == 0) atomicAdd(&cnt[cur], c0);
}

__global__ void fc_kernel(const float* __restrict__ sums, const int* __restrict__ cnt,
                          const float* __restrict__ fcW, const float* __restrict__ fcb,
                          float* __restrict__ out) {
    int g = (blockIdx.x * blockDim.x + threadIdx.x) >> 6;
    int lane = threadIdx.x & 63;
    if (g >= NG) return;
    float c = fmaxf((float)cnt[g], 1.f);
    float val = (sums[g * 64 + lane] / c) * fcW[lane];
#pragma unroll
    for (int off = 32; off; off >>= 1) val += __shfl_down(val, off, 64);
    if (lane == 0) out[g] = 1.f / (1.f + expf(-(val + fcb[0])));
}

// ---------------------------------------------------------------------------
extern "C" void kernel_launch(void* const* d_in, const int* in_sizes, int n_in,
                              void* d_out, int out_size, void* d_ws, size_t ws_size,
                              hipStream_t stream) {
    const float* x   = (const float*)d_in[0];
    const int* ei    = (const int*)d_in[1];
    const int* batch = (const int*)d_in[2];
    const float* W[3], *attS[3], *attD[3], *bias[3], *gamma[3], *beta[3], *mean[3], *var[3];
    for (int l = 0; l < 3; ++l) {
        W[l]     = (const float*)d_in[3 + 8 * l + 0];
        attS[l]  = (const float*)d_in[3 + 8 * l + 1];
        attD[l]  = (const float*)d_in[3 + 8 * l + 2];
        bias[l]  = (const float*)d_in[3 + 8 * l + 3];
        gamma[l] = (const float*)d_in[3 + 8 * l + 4];
        beta[l]  = (const float*)d_in[3 + 8 * l + 5];
        mean[l]  = (const float*)d_in[3 + 8 * l + 6];
        var[l]   = (const float*)d_in[3 + 8 * l + 7];
    }
    const float* fcW = (const float*)d_in[27];
    const float* fcb = (const float*)d_in[28];
    float* out = (float*)d_out;               // [128] pooled sigmoid
    float* alpha_out = (float*)d_out + NG;    // [850000*4] layer-0 alpha

    // Workspace carve-up (256B aligned)
    char* p = (char*)d_ws;
    auto carve = [&](size_t bytes) {
        char* q = p;
        p += (bytes + 255) & ~(size_t)255;
        return q;
    };
    _Float16* Xh    = (_Float16*)carve(sizeof(_Float16) * NN * INDIM);
    _Float16* Wh    = (_Float16*)carve(sizeof(_Float16) * 16384);
    _Float16* Hh    = (_Float16*)carve(sizeof(_Float16) * NN * 64);  // gemm out
    _Float16* Hn    = (_Float16*)carve(sizeof(_Float16) * NN * 64);  // aggr out
    float* AS       = (float*)carve(sizeof(float) * NN * 4);
    float* AD       = (float*)carve(sizeof(float) * NN * 4);
    float* Z        = (float*)carve(sizeof(float) * NN * 4);
    int*   rowstart = (int*)carve(sizeof(int) * NN);
    int*   deg      = (int*)carve(sizeof(int) * NN);
    int*   rank     = (int*)carve(sizeof(int) * ETOT);
    int*   bsums    = (int*)carve(sizeof(int) * 64);
    int*   csr      = (int*)carve(sizeof(int) * ETOT);
    float* psums    = (float*)carve(sizeof(float) * NG * 64);
    int*   pcnt     = (int*)carve(sizeof(int) * NG);

    // fp16 converts + zero-init, one launch
    prep_kernel<<<(PREP_TOT + 255) / 256, 256, 0, stream>>>(
        x, W[0], W[1], W[2], Xh, Wh, deg, psums, pcnt);

    // CSR build
    int nbScan = (NN + 1023) / 1024;
    degree_kernel<<<(ETOT + 255) / 256, 256, 0, stream>>>(ei, deg, rank);
    scan_block_kernel<<<nbScan, 1024, 0, stream>>>(deg, rowstart, bsums);
    scan_sums_kernel<<<1, 64, 0, stream>>>(bsums, nbScan);
    add_offsets_kernel<<<(NN + 255) / 256, 256, 0, stream>>>(rowstart, bsums);
    scatter_kernel<<<(ETOT + 255) / 256, 256, 0, stream>>>(ei, rowstart, rank, csr);

    int edgeBlocks = (NN * 64 + 255) / 256;
    int posBlocks = (ETOT + 255) / 256;
    int gemmBlocks = (NN + 63) / 64;   // 782

    // Layer 0 (K=128), writes Z then alpha
    gemm_att_kernel<128><<<gemmBlocks, 256, 0, stream>>>(Xh, Wh, attS[0], attD[0],
                                                         Hh, AS, AD);
    edge_aggr_kernel<true><<<edgeBlocks, 256, 0, stream>>>(
        Hh, AS, AD, rowstart, deg, csr,
        bias[0], gamma[0], beta[0], mean[0], var[0], Hn, Z);
    alpha_kernel<<<posBlocks, 256, 0, stream>>>(ei, AS, AD, Z, alpha_out);

    // Layer 1 (K=64)
    gemm_att_kernel<64><<<gemmBlocks, 256, 0, stream>>>(Hn, Wh + 8192, attS[1], attD[1],
                                                        Hh, AS, AD);
    edge_aggr_kernel<false><<<edgeBlocks, 256, 0, stream>>>(
        Hh, AS, AD, rowstart, deg, csr,
        bias[1], gamma[1], beta[1], mean[1], var[1], Hn, nullptr);

    // Layer 2 (K=64)
    gemm_att_kernel<64><<<gemmBlocks, 256, 0, stream>>>(Hn, Wh + 12288, attS[2], attD[2],
                                                        Hh, AS, AD);
    edge_aggr_kernel<false><<<edgeBlocks, 256, 0, stream>>>(
        Hh, AS, AD, rowstart, deg, csr,
        bias[2], gamma[2], beta[2], mean[2], var[2], Hn, nullptr);

    // Pool + FC
    int poolWaves = (NN + 63) / 64;
    pool_kernel<<<(poolWaves * 64 + 255) / 256, 256, 0, stream>>>(
        (const __half*)Hn, batch, psums, pcnt);
    fc_kernel<<<(NG * 64 + 255) / 256, 256, 0, stream>>>(psums, pcnt, fcW, fcb, out);
}

// Round 14
// 364.369 us; speedup vs baseline: 1.0233x; 1.0233x over previous
//
#include <hip/hip_runtime.h>
#include <hip/hip_fp16.h>
#include <math.h>

// Problem constants (match reference)
#define NN     50000
#define EE     800000
#define ETOT   (EE + NN)      // edges + self loops = 850000
#define INDIM  128
#define HEADS  4
#define NG     128
#define NEGS   0.2f
#define BNEPS  1e-5f

typedef _Float16 half8 __attribute__((ext_vector_type(8)));
typedef _Float16 half4v __attribute__((ext_vector_type(4)));
typedef float floatx4 __attribute__((ext_vector_type(4)));

// R14: aggregator reverted to R12 quarter-wave (R13 eighth-wave regressed
// 365.6->372.8: same FMA/lane count, bigger epilogue). scan_sums_kernel
// (1 thread x 49 DEPENDENT global RMWs ~= 10-18us latency chain) eliminated:
// add_offsets computes its own block prefix in parallel. rowstart is NN+1 so
// edge_aggr uses rowstart[v+1]-rowstart[v] (no deg load).

// ---------------------------------------------------------------------------
// CSR build. R6: rank captured in degree_kernel (already pays the random
// atomic); scatter is atomic-free. R11: csr = src only (4B scatter payload).
__global__ void degree_kernel(const int* __restrict__ ei, int* __restrict__ deg,
                              int* __restrict__ rank) {
    int e = blockIdx.x * blockDim.x + threadIdx.x;
    if (e >= ETOT) return;
    int d = (e < EE) ? ei[EE + e] : (e - EE);
    rank[e] = atomicAdd(&deg[d], 1);
}

__global__ void scan_block_kernel(const int* __restrict__ deg, int* __restrict__ rowstart,
                                  int* __restrict__ bsums) {
    __shared__ int tmp[1024];
    int tid = threadIdx.x;
    int i = blockIdx.x * 1024 + tid;
    int v = (i < NN) ? deg[i] : 0;
    tmp[tid] = v;
    __syncthreads();
    for (int off = 1; off < 1024; off <<= 1) {
        int t = (tid >= off) ? tmp[tid - off] : 0;
        __syncthreads();
        tmp[tid] += t;
        __syncthreads();
    }
    if (i < NN) rowstart[i] = tmp[tid] - v;   // exclusive within block
    if (tid == 1023) bsums[blockIdx.x] = tmp[tid];
}

// Each thread sums its block-prefix from bsums (<=48 L2-hot loads, parallel)
// — replaces the serial 1-thread scan_sums kernel entirely.
__global__ void add_offsets_kernel(int* __restrict__ rowstart, const int* __restrict__ bsums) {
    int i = blockIdx.x * blockDim.x + threadIdx.x;
    if (i == 0) rowstart[NN] = ETOT;
    if (i >= NN) return;
    int nbk = i >> 10;
    int off = 0;
    for (int j = 0; j < nbk; ++j) off += bsums[j];
    rowstart[i] += off;
}

// Atomic-free scatter, 4B payload (src only).
__global__ void scatter_kernel(const int* __restrict__ ei, const int* __restrict__ rowstart,
                               const int* __restrict__ rank, int* __restrict__ csr) {
    int e = blockIdx.x * blockDim.x + threadIdx.x;
    if (e >= ETOT) return;
    int s, d;
    if (e < EE) { s = ei[e]; d = ei[EE + e]; }
    else        { s = e - EE; d = e - EE; }
    int pos = rowstart[d] + rank[e];
    csr[pos] = s;
}

// ---------------------------------------------------------------------------
// Fused prep: fp32->fp16 converts (X, all W) + zero-init deg/psums/pcnt.
#define NX8 (NN * INDIM / 8)
#define PREP_TOT (NX8 + 2048 + NN + NG * 64 + NG)
__global__ __launch_bounds__(256) void prep_kernel(const float* __restrict__ x,
                                                   const float* __restrict__ W0,
                                                   const float* __restrict__ W1,
                                                   const float* __restrict__ W2,
                                                   _Float16* __restrict__ Xh,
                                                   _Float16* __restrict__ Wh,
                                                   int* __restrict__ deg,
                                                   float* __restrict__ psums,
                                                   int* __restrict__ pcnt) {
    int i = blockIdx.x * blockDim.x + threadIdx.x;     // x8 floats
    if (i < NX8) {
        float4 v0 = *(const float4*)(x + (size_t)i * 8);
        float4 v1 = *(const float4*)(x + (size_t)i * 8 + 4);
        half8 o;
        o[0] = (_Float16)v0.x; o[1] = (_Float16)v0.y;
        o[2] = (_Float16)v0.z; o[3] = (_Float16)v0.w;
        o[4] = (_Float16)v1.x; o[5] = (_Float16)v1.y;
        o[6] = (_Float16)v1.z; o[7] = (_Float16)v1.w;
        *(half8*)(Xh + (size_t)i * 8) = o;
    } else if (i < NX8 + 2048) {
        int wi = (i - NX8) * 8;            // 8-groups never straddle W arrays
#pragma unroll
        for (int j = 0; j < 8; ++j) {
            int idx = wi + j;
            float v = (idx < 8192) ? W0[idx]
                    : ((idx < 12288) ? W1[idx - 8192] : W2[idx - 12288]);
            Wh[idx] = (_Float16)v;
        }
    } else if (i < NX8 + 2048 + NN) {
        deg[i - NX8 - 2048] = 0;
    } else if (i < NX8 + 2048 + NN + NG * 64) {
        psums[i - NX8 - 2048 - NN] = 0.f;
    } else if (i < PREP_TOT) {
        pcnt[i - NX8 - 2048 - NN - NG * 64] = 0;
    }
}

// ---------------------------------------------------------------------------
// MFMA GEMM (h = x @ W^T) + attention dots. Block = 4 waves; each wave owns
// 16 nodes x 64 cols = 4 col-tiles of 16x16, K in 32-chunks.
// A frag: X[wbase + (lane&15)][kb*32 + quad*8 ..+8]; B frag same shape on W.
// C/D: node = wbase + quad*4 + reg, col = t*16 + (lane&15).
template <int DD>
__global__ __launch_bounds__(256) void gemm_att_kernel(
    const _Float16* __restrict__ X, const _Float16* __restrict__ Wh,
    const float* __restrict__ attS, const float* __restrict__ attD,
    _Float16* __restrict__ H, float* __restrict__ AS, float* __restrict__ AD) {
    constexpr int KB = DD / 32;
    int tid = threadIdx.x;
    int wv = tid >> 6;
    int lane = tid & 63;
    int quad = lane >> 4;
    int n = lane & 15;
    int wbase = blockIdx.x * 64 + wv * 16;

    int arow = wbase + n;
    if (arow >= NN) arow = NN - 1;          // clamp (stores are guarded)
    half8 a[KB];
#pragma unroll
    for (int kb = 0; kb < KB; ++kb)
        a[kb] = *(const half8*)(X + (size_t)arow * DD + kb * 32 + quad * 8);

    floatx4 c[4];
#pragma unroll
    for (int t = 0; t < 4; ++t) {
        floatx4 acc = {0.f, 0.f, 0.f, 0.f};
#pragma unroll
        for (int kb = 0; kb < KB; ++kb) {
            half8 b = *(const half8*)(Wh + (size_t)(t * 16 + n) * DD + kb * 32 + quad * 8);
            acc = __builtin_amdgcn_mfma_f32_16x16x32_f16(a[kb], b, acc, 0, 0, 0);
        }
        c[t] = acc;
    }

    float as_l[4], ad_l[4];
#pragma unroll
    for (int t = 0; t < 4; ++t) {
        as_l[t] = attS[t * 16 + n];
        ad_l[t] = attD[t * 16 + n];
    }
#pragma unroll
    for (int r = 0; r < 4; ++r) {
        int node = wbase + quad * 4 + r;
        bool ok = node < NN;
#pragma unroll
        for (int t = 0; t < 4; ++t) {
            float h = c[t][r];
            if (ok) H[(size_t)node * 64 + t * 16 + n] = (_Float16)h;
            float vs = h * as_l[t];
            float vd = h * ad_l[t];
#pragma unroll
            for (int off = 8; off; off >>= 1) {
                vs += __shfl_down(vs, off, 16);
                vd += __shfl_down(vd, off, 16);
            }
            if (ok && n == 0) {
                AS[node * 4 + t] = vs;
                AD[node * 4 + t] = vd;
            }
        }
    }
}

// ---------------------------------------------------------------------------
// Per-node aggregation, quarter-wave edge parallelism (R12 — measured best;
// R13 eighth-wave regressed). quarter q = lane>>4 serves edges k+q*4..+3 per
// 16-edge iteration; each lane covers 4 channels (ch4 = (lane&15)*4) via
// fp16x4 gathers. Cross-quarter combine: shfl_xor(16)+(32). Inline attention
// weights (R7); no max-subtraction (logits O(1), exp cannot overflow).
template <bool WRITE_Z>
__global__ __launch_bounds__(256) void edge_aggr_kernel(
    const _Float16* __restrict__ H, const float* __restrict__ AS,
    const float* __restrict__ AD,
    const int* __restrict__ rowstart,
    const int* __restrict__ csr,
    const float* __restrict__ bias, const float* __restrict__ gamma,
    const float* __restrict__ beta, const float* __restrict__ mean,
    const float* __restrict__ var, _Float16* __restrict__ Hout,
    float* __restrict__ Z) {
    int v = (blockIdx.x * blockDim.x + threadIdx.x) >> 6;
    if (v >= NN) return;
    int lane = threadIdx.x & 63;
    int q = lane >> 4;
    int l16 = lane & 15;
    int head = l16 >> 2;
    int ch4 = l16 * 4;
    float adv = AD[v * 4 + head];
    int start = rowstart[v];
    int cnt = rowstart[v + 1] - start;   // >= 1 (self loop)
    const int* srow = csr + start;
    float z = 0.f;
    float acc0 = 0.f, acc1 = 0.f, acc2 = 0.f, acc3 = 0.f;
    int k = 0;
    for (; k + 16 <= cnt; k += 16) {
        int b = k + q * 4;
        int s0 = srow[b + 0];
        int s1 = srow[b + 1];
        int s2 = srow[b + 2];
        int s3 = srow[b + 3];
        float a0 = AS[(size_t)s0 * 4 + head];
        float a1 = AS[(size_t)s1 * 4 + head];
        float a2 = AS[(size_t)s2 * 4 + head];
        float a3 = AS[(size_t)s3 * 4 + head];
        half4v h0 = *(const half4v*)(H + (size_t)s0 * 64 + ch4);
        half4v h1 = *(const half4v*)(H + (size_t)s1 * 64 + ch4);
        half4v h2 = *(const half4v*)(H + (size_t)s2 * 64 + ch4);
        half4v h3 = *(const half4v*)(H + (size_t)s3 * 64 + ch4);
        float l0 = a0 + adv; l0 = l0 > 0.f ? l0 : NEGS * l0; float p0 = __expf(l0);
        float l1 = a1 + adv; l1 = l1 > 0.f ? l1 : NEGS * l1; float p1 = __expf(l1);
        float l2 = a2 + adv; l2 = l2 > 0.f ? l2 : NEGS * l2; float p2 = __expf(l2);
        float l3 = a3 + adv; l3 = l3 > 0.f ? l3 : NEGS * l3; float p3 = __expf(l3);
        z += (p0 + p1) + (p2 + p3);
        acc0 = fmaf(p0, (float)h0[0], acc0); acc1 = fmaf(p0, (float)h0[1], acc1);
        acc2 = fmaf(p0, (float)h0[2], acc2); acc3 = fmaf(p0, (float)h0[3], acc3);
        acc0 = fmaf(p1, (float)h1[0], acc0); acc1 = fmaf(p1, (float)h1[1], acc1);
        acc2 = fmaf(p1, (float)h1[2], acc2); acc3 = fmaf(p1, (float)h1[3], acc3);
        acc0 = fmaf(p2, (float)h2[0], acc0); acc1 = fmaf(p2, (float)h2[1], acc1);
        acc2 = fmaf(p2, (float)h2[2], acc2); acc3 = fmaf(p2, (float)h2[3], acc3);
        acc0 = fmaf(p3, (float)h3[0], acc0); acc1 = fmaf(p3, (float)h3[1], acc1);
        acc2 = fmaf(p3, (float)h3[2], acc2); acc3 = fmaf(p3, (float)h3[3], acc3);
    }
    for (; k < cnt; k += 4) {
        int idx = k + q;
        if (idx < cnt) {
            int s = srow[idx];
            float a = AS[(size_t)s * 4 + head];
            half4v hv = *(const half4v*)(H + (size_t)s * 64 + ch4);
            float l = a + adv; l = l > 0.f ? l : NEGS * l;
            float p = __expf(l);
            z += p;
            acc0 = fmaf(p, (float)hv[0], acc0);
            acc1 = fmaf(p, (float)hv[1], acc1);
            acc2 = fmaf(p, (float)hv[2], acc2);
            acc3 = fmaf(p, (float)hv[3], acc3);
        }
    }
    // combine the four quarter-wave partial sums
    z    += __shfl_xor(z, 16);    z    += __shfl_xor(z, 32);
    acc0 += __shfl_xor(acc0, 16); acc0 += __shfl_xor(acc0, 32);
    acc1 += __shfl_xor(acc1, 16); acc1 += __shfl_xor(acc1, 32);
    acc2 += __shfl_xor(acc2, 16); acc2 += __shfl_xor(acc2, 32);
    acc3 += __shfl_xor(acc3, 16); acc3 += __shfl_xor(acc3, 32);
    if (q == 0) {
        if (WRITE_Z && (l16 & 3) == 0) Z[v * 4 + head] = z;
        float4 bi = *(const float4*)(bias + ch4);
        float4 ga = *(const float4*)(gamma + ch4);
        float4 be = *(const float4*)(beta + ch4);
        float4 mu = *(const float4*)(mean + ch4);
        float4 va = *(const float4*)(var + ch4);
        float r0 = fmaxf(acc0 / z + bi.x, 0.f);
        float r1 = fmaxf(acc1 / z + bi.y, 0.f);
        float r2 = fmaxf(acc2 / z + bi.z, 0.f);
        float r3 = fmaxf(acc3 / z + bi.w, 0.f);
        r0 = ga.x * (r0 - mu.x) * rsqrtf(va.x + BNEPS) + be.x;
        r1 = ga.y * (r1 - mu.y) * rsqrtf(va.y + BNEPS) + be.y;
        r2 = ga.z * (r2 - mu.z) * rsqrtf(va.z + BNEPS) + be.z;
        r3 = ga.w * (r3 - mu.w) * rsqrtf(va.w + BNEPS) + be.w;
        half4v o;
        o[0] = (_Float16)r0;
        o[1] = (_Float16)r1;
        o[2] = (_Float16)r2;
        o[3] = (_Float16)r3;
        *(half4v*)(Hout + (size_t)v * 64 + ch4) = o;
    }
}

// ---------------------------------------------------------------------------
// Layer-0 alpha, ORIGINAL edge order (R11): needs no csr; recomputes p from
// AS/AD (identical formula+inputs as aggr => identical values), divides by Z,
// writes coalesced float4 at alpha_out + e*4.
__global__ __launch_bounds__(256) void alpha_kernel(
    const int* __restrict__ ei,
    const float* __restrict__ AS, const float* __restrict__ AD,
    const float* __restrict__ Z, float* __restrict__ alpha_out) {
    int e = blockIdx.x * blockDim.x + threadIdx.x;
    if (e >= ETOT) return;
    int s, d;
    if (e < EE) { s = ei[e]; d = ei[EE + e]; }
    else        { s = e - EE; d = e - EE; }
    float4 as = *(const float4*)(AS + (size_t)s * 4);
    float4 ad = *(const float4*)(AD + (size_t)d * 4);
    float4 z4 = *(const float4*)(Z + (size_t)d * 4);
    float l;
    float4 a;
    l = as.x + ad.x; l = l > 0.f ? l : NEGS * l; a.x = __expf(l) / z4.x;
    l = as.y + ad.y; l = l > 0.f ? l : NEGS * l; a.y = __expf(l) / z4.y;
    l = as.z + ad.z; l = l > 0.f ? l : NEGS * l; a.z = __expf(l) / z4.z;
    l = as.w + ad.w; l = l > 0.f ? l : NEGS * l; a.w = __expf(l) / z4.w;
    *(float4*)(alpha_out + (size_t)e * 4) = a;
}

// ---------------------------------------------------------------------------
// Mean pool over sorted batch ids (fp16 input): one wave per 64-node chunk,
// local accumulation, atomic flush on graph-id change.
__global__ __launch_bounds__(256) void pool_kernel(const __half* __restrict__ H,
                                                   const int* __restrict__ batch,
                                                   float* __restrict__ sums,
                                                   int* __restrict__ cnt) {
    int wid = (blockIdx.x * blockDim.x + threadIdx.x) >> 6;
    int lane = threadIdx.x & 63;
    int base = wid * 64;
    if (base >= NN) return;
    int end = min(base + 64, NN);
    int cur = batch[base];
    float acc = 0.f;
    int c0 = 0;
    for (int i = base; i < end; ++i) {
        int g = batch[i];
        if (g != cur) {
            atomicAdd(&sums[cur * 64 + lane], acc);
            if (lane == 0) atomicAdd(&cnt[cur], c0);
            cur = g; acc = 0.f; c0 = 0;
        }
        acc += __half2float(H[(size_t)i * 64 + lane]);
        c0++;
    }
    atomicAdd(&sums[cur * 64 + lane], acc);
    if (lane == 0) atomicAdd(&cnt[cur], c0);
}

__global__ void fc_kernel(const float* __restrict__ sums, const int* __restrict__ cnt,
                          const float* __restrict__ fcW, const float* __restrict__ fcb,
                          float* __restrict__ out) {
    int g = (blockIdx.x * blockDim.x + threadIdx.x) >> 6;
    int lane = threadIdx.x & 63;
    if (g >= NG) return;
    float c = fmaxf((float)cnt[g], 1.f);
    float val = (sums[g * 64 + lane] / c) * fcW[lane];
#pragma unroll
    for (int off = 32; off; off >>= 1) val += __shfl_down(val, off, 64);
    if (lane == 0) out[g] = 1.f / (1.f + expf(-(val + fcb[0])));
}

// ---------------------------------------------------------------------------
extern "C" void kernel_launch(void* const* d_in, const int* in_sizes, int n_in,
                              void* d_out, int out_size, void* d_ws, size_t ws_size,
                              hipStream_t stream) {
    const float* x   = (const float*)d_in[0];
    const int* ei    = (const int*)d_in[1];
    const int* batch = (const int*)d_in[2];
    const float* W[3], *attS[3], *attD[3], *bias[3], *gamma[3], *beta[3], *mean[3], *var[3];
    for (int l = 0; l < 3; ++l) {
        W[l]     = (const float*)d_in[3 + 8 * l + 0];
        attS[l]  = (const float*)d_in[3 + 8 * l + 1];
        attD[l]  = (const float*)d_in[3 + 8 * l + 2];
        bias[l]  = (const float*)d_in[3 + 8 * l + 3];
        gamma[l] = (const float*)d_in[3 + 8 * l + 4];
        beta[l]  = (const float*)d_in[3 + 8 * l + 5];
        mean[l]  = (const float*)d_in[3 + 8 * l + 6];
        var[l]   = (const float*)d_in[3 + 8 * l + 7];
    }
    const float* fcW = (const float*)d_in[27];
    const float* fcb = (const float*)d_in[28];
    float* out = (float*)d_out;               // [128] pooled sigmoid
    float* alpha_out = (float*)d_out + NG;    // [850000*4] layer-0 alpha

    // Workspace carve-up (256B aligned)
    char* p = (char*)d_ws;
    auto carve = [&](size_t bytes) {
        char* q = p;
        p += (bytes + 255) & ~(size_t)255;
        return q;
    };
    _Float16* Xh    = (_Float16*)carve(sizeof(_Float16) * NN * INDIM);
    _Float16* Wh    = (_Float16*)carve(sizeof(_Float16) * 16384);
    _Float16* Hh    = (_Float16*)carve(sizeof(_Float16) * NN * 64);  // gemm out
    _Float16* Hn    = (_Float16*)carve(sizeof(_Float16) * NN * 64);  // aggr out
    float* AS       = (float*)carve(sizeof(float) * NN * 4);
    float* AD       = (float*)carve(sizeof(float) * NN * 4);
    float* Z        = (float*)carve(sizeof(float) * NN * 4);
    int*   rowstart = (int*)carve(sizeof(int) * (NN + 1));
    int*   deg      = (int*)carve(sizeof(int) * NN);
    int*   rank     = (int*)carve(sizeof(int) * ETOT);
    int*   bsums    = (int*)carve(sizeof(int) * 64);
    int*   csr      = (int*)carve(sizeof(int) * ETOT);
    float* psums    = (float*)carve(sizeof(float) * NG * 64);
    int*   pcnt     = (int*)carve(sizeof(int) * NG);

    // fp16 converts + zero-init, one launch
    prep_kernel<<<(PREP_TOT + 255) / 256, 256, 0, stream>>>(
        x, W[0], W[1], W[2], Xh, Wh, deg, psums, pcnt);

    // CSR build (scan_sums folded into add_offsets — no serial kernel)
    int nbScan = (NN + 1023) / 1024;
    degree_kernel<<<(ETOT + 255) / 256, 256, 0, stream>>>(ei, deg, rank);
    scan_block_kernel<<<nbScan, 1024, 0, stream>>>(deg, rowstart, bsums);
    add_offsets_kernel<<<(NN + 255) / 256, 256, 0, stream>>>(rowstart, bsums);
    scatter_kernel<<<(ETOT + 255) / 256, 256, 0, stream>>>(ei, rowstart, rank, csr);

    int edgeBlocks = (NN * 64 + 255) / 256;
    int posBlocks = (ETOT + 255) / 256;
    int gemmBlocks = (NN + 63) / 64;   // 782

    // Layer 0 (K=128), writes Z then alpha
    gemm_att_kernel<128><<<gemmBlocks, 256, 0, stream>>>(Xh, Wh, attS[0], attD[0],
                                                         Hh, AS, AD);
    edge_aggr_kernel<true><<<edgeBlocks, 256, 0, stream>>>(
        Hh, AS, AD, rowstart, csr,
        bias[0], gamma[0], beta[0], mean[0], var[0], Hn, Z);
    alpha_kernel<<<posBlocks, 256, 0, stream>>>(ei, AS, AD, Z, alpha_out);

    // Layer 1 (K=64)
    gemm_att_kernel<64><<<gemmBlocks, 256, 0, stream>>>(Hn, Wh + 8192, attS[1], attD[1],
                                                        Hh, AS, AD);
    edge_aggr_kernel<false><<<edgeBlocks, 256, 0, stream>>>(
        Hh, AS, AD, rowstart, csr,
        bias[1], gamma[1], beta[1], mean[1], var[1], Hn, nullptr);

    // Layer 2 (K=64)
    gemm_att_kernel<64><<<gemmBlocks, 256, 0, stream>>>(Hn, Wh + 12288, attS[2], attD[2],
                                                        Hh, AS, AD);
    edge_aggr_kernel<false><<<edgeBlocks, 256, 0, stream>>>(
        Hh, AS, AD, rowstart, csr,
        bias[2], gamma[2], beta[2], mean[2], var[2], Hn, nullptr);

    // Pool + FC
    int poolWaves = (NN + 63) / 64;
    pool_kernel<<<(poolWaves * 64 + 255) / 256, 256, 0, stream>>>(
        (const __half*)Hn, batch, psums, pcnt);
    fc_kernel<<<(NG * 64 + 255) / 256, 256, 0, stream>>>(psums, pcnt, fcW, fcb, out);
}